// Round 1
// baseline (5718.831 us; speedup 1.0000x reference)
//
#include <hip/hip_runtime.h>
#include <hip/hip_bf16.h>

typedef __attribute__((ext_vector_type(8))) short short8;
typedef __attribute__((ext_vector_type(4))) float f32x4;

#define B_  2
#define T_  1024
#define D_  1024
#define H_  16
#define HD_ 64
#define E_  8
#define FH_ 4096
#define NT  (B_*T_)   // 2048 tokens
#define S_  (2*T_)    // 2048 concat KV length

// ---------------- RMSNorm: one token per block, 256 threads, float4 ----------------
__global__ __launch_bounds__(256) void k_rmsnorm(const float* __restrict__ x,
                                                 const float* __restrict__ w,
                                                 float* __restrict__ o) {
    int row = blockIdx.x, tid = threadIdx.x;
    const float4* x4 = (const float4*)(x + (size_t)row * D_);
    float4 v = x4[tid];
    float ss = v.x*v.x + v.y*v.y + v.z*v.z + v.w*v.w;
    #pragma unroll
    for (int off = 32; off; off >>= 1) ss += __shfl_xor(ss, off);
    __shared__ float wsum[4];
    if ((tid & 63) == 0) wsum[tid >> 6] = ss;
    __syncthreads();
    float tot = wsum[0] + wsum[1] + wsum[2] + wsum[3];
    float scale = rsqrtf(tot * (1.0f / D_) + 1e-6f);
    float4 wv = ((const float4*)w)[tid];
    float4 r;
    r.x = v.x * scale * wv.x; r.y = v.y * scale * wv.y;
    r.z = v.z * scale * wv.z; r.w = v.w * scale * wv.w;
    ((float4*)(o + (size_t)row * D_))[tid] = r;
}

// ---------------- bf16 MFMA GEMM: C[M,N] = A[M,K] * B[K,N], 64x64 tile ----------------
__global__ __launch_bounds__(256) void k_gemm(const float* __restrict__ A,
                                              const float* __restrict__ B,
                                              float* __restrict__ C,
                                              int M, int N, int K) {
    __shared__ __align__(16) __hip_bfloat16 As[64][32];   // [m][k]
    __shared__ __align__(16) __hip_bfloat16 Bs[64][32];   // [n][k]  (B^T tile)
    const int tid  = threadIdx.x;
    const int m0   = blockIdx.y << 6, n0 = blockIdx.x << 6;
    const int lane = tid & 63, wid = tid >> 6;
    const int wr   = wid >> 1, wc = wid & 1;
    const int fr   = lane & 15, fk = (lane >> 4) << 3;
    f32x4 acc00 = {0.f,0.f,0.f,0.f};
    f32x4 acc01 = acc00, acc10 = acc00, acc11 = acc00;
    const int arow = tid >> 2, ak0 = (tid & 3) << 3;   // A: 64 rows x 32 k
    const int bk   = tid >> 3, bn0 = (tid & 7) << 3;   // B: 32 k   x 64 n

    for (int kk = 0; kk < K; kk += 32) {
        const float* ap = A + (size_t)(m0 + arow) * K + kk + ak0;
        float4 a0v = *(const float4*)ap;
        float4 a1v = *(const float4*)(ap + 4);
        const float* bp = B + (size_t)(kk + bk) * N + n0 + bn0;
        float4 b0v = *(const float4*)bp;
        float4 b1v = *(const float4*)(bp + 4);
        __hip_bfloat16* ad = &As[arow][ak0];
        ad[0] = __float2bfloat16(a0v.x); ad[1] = __float2bfloat16(a0v.y);
        ad[2] = __float2bfloat16(a0v.z); ad[3] = __float2bfloat16(a0v.w);
        ad[4] = __float2bfloat16(a1v.x); ad[5] = __float2bfloat16(a1v.y);
        ad[6] = __float2bfloat16(a1v.z); ad[7] = __float2bfloat16(a1v.w);
        Bs[bn0+0][bk] = __float2bfloat16(b0v.x); Bs[bn0+1][bk] = __float2bfloat16(b0v.y);
        Bs[bn0+2][bk] = __float2bfloat16(b0v.z); Bs[bn0+3][bk] = __float2bfloat16(b0v.w);
        Bs[bn0+4][bk] = __float2bfloat16(b1v.x); Bs[bn0+5][bk] = __float2bfloat16(b1v.y);
        Bs[bn0+6][bk] = __float2bfloat16(b1v.z); Bs[bn0+7][bk] = __float2bfloat16(b1v.w);
        __syncthreads();
        short8 a0 = *(const short8*)&As[(wr<<5) +      fr][fk];
        short8 a1 = *(const short8*)&As[(wr<<5) + 16 + fr][fk];
        short8 b0 = *(const short8*)&Bs[(wc<<5) +      fr][fk];
        short8 b1 = *(const short8*)&Bs[(wc<<5) + 16 + fr][fk];
        acc00 = __builtin_amdgcn_mfma_f32_16x16x32_bf16(a0, b0, acc00, 0, 0, 0);
        acc01 = __builtin_amdgcn_mfma_f32_16x16x32_bf16(a0, b1, acc01, 0, 0, 0);
        acc10 = __builtin_amdgcn_mfma_f32_16x16x32_bf16(a1, b0, acc10, 0, 0, 0);
        acc11 = __builtin_amdgcn_mfma_f32_16x16x32_bf16(a1, b1, acc11, 0, 0, 0);
        __syncthreads();
    }
    const int fq = lane >> 4;
    const int crow = m0 + (wr << 5) + (fq << 2);
    const int ccol = n0 + (wc << 5) + fr;
    #pragma unroll
    for (int r = 0; r < 4; r++) {
        C[(size_t)(crow +      r) * N + ccol     ] = acc00[r];
        C[(size_t)(crow +      r) * N + ccol + 16] = acc01[r];
        C[(size_t)(crow + 16 + r) * N + ccol     ] = acc10[r];
        C[(size_t)(crow + 16 + r) * N + ccol + 16] = acc11[r];
    }
}

// ---------------- RoPE (q,k) in qkv buffer + build concat K/V ----------------
// Kc/Vc layout: [b][h][s][d], s in [0,T) = memory (k_xl+pos_emb / v_xl), [T,2T) = current
__global__ __launch_bounds__(256) void k_rope(float* __restrict__ qkv,
                                              const float* __restrict__ fc,
                                              const float* __restrict__ fs,
                                              const float* __restrict__ k_xl,
                                              const float* __restrict__ v_xl,
                                              const float* __restrict__ pos,
                                              float* __restrict__ Kc,
                                              float* __restrict__ Vc) {
    int bt = blockIdx.x;              // b*T + t
    int b = bt >> 10, t = bt & (T_ - 1);
    int tid = threadIdx.x;
    // rope pairs: 512 pairs per token
    for (int p = tid; p < D_ / 2; p += 256) {
        int h = p >> 5, i = p & 31;   // HD/2 = 32 pairs per head
        float c = fc[t * 32 + i], s = fs[t * 32 + i];
        size_t qoff = (size_t)bt * 3072 + h * 64 + 2 * i;
        float qr = qkv[qoff], qi = qkv[qoff + 1];
        qkv[qoff]     = qr * c - qi * s;
        qkv[qoff + 1] = qr * s + qi * c;
        float kr = qkv[qoff + 1024], ki = qkv[qoff + 1025];
        size_t koff = ((size_t)(b * H_ + h) * S_ + T_ + t) * HD_ + 2 * i;
        Kc[koff]     = kr * c - ki * s;
        Kc[koff + 1] = kr * s + ki * c;
        Vc[koff]     = qkv[qoff + 2048];
        Vc[koff + 1] = qkv[qoff + 2049];
    }
    // memory rows (s = t): k_xl + pos_emb, v_xl (no rope)
    for (int d = tid; d < D_; d += 256) {
        int h = d >> 6, dd = d & 63;
        size_t src = (size_t)bt * D_ + d;
        size_t dst = ((size_t)(b * H_ + h) * S_ + t) * HD_ + dd;
        Kc[dst] = k_xl[src] + pos[(size_t)t * D_ + d];
        Vc[dst] = v_xl[src];
    }
}

// ---------------- attention: one (b,h,t) q-row per block ----------------
__global__ __launch_bounds__(256) void k_attn(const float* __restrict__ qkv,
                                              const float* __restrict__ Kc,
                                              const float* __restrict__ Vc,
                                              float* __restrict__ y,
                                              const int* __restrict__ pcausal) {
    __shared__ float p_lds[S_];
    __shared__ float q_s[HD_];
    __shared__ float redm[4], reds[4];
    __shared__ float part[4][HD_];
    int t  = blockIdx.x & (T_ - 1);
    int bh = blockIdx.x >> 10;
    int b  = bh >> 4, h = bh & 15;
    int tid = threadIdx.x;
    int causal = pcausal[0];
    if (tid < HD_) q_s[tid] = qkv[(size_t)(b * T_ + t) * 3072 + h * 64 + tid];
    __syncthreads();

    const float* kb = Kc + (size_t)bh * S_ * HD_;
    float sc[8];
    float lmax = -1e30f;
    #pragma unroll
    for (int i = 0; i < 8; i++) {
        int s = tid + 256 * i;
        const float* kr = kb + (size_t)s * HD_;
        float acc = 0.f;
        #pragma unroll
        for (int d = 0; d < HD_; d += 4) {
            float4 kv = *(const float4*)(kr + d);
            acc += q_s[d] * kv.x + q_s[d+1] * kv.y + q_s[d+2] * kv.z + q_s[d+3] * kv.w;
        }
        acc *= 0.125f;   // 1/sqrt(64)
        if (causal && s > t) acc = -1e30f;
        sc[i] = acc;
        lmax = fmaxf(lmax, acc);
    }
    #pragma unroll
    for (int off = 32; off; off >>= 1) lmax = fmaxf(lmax, __shfl_xor(lmax, off));
    if ((tid & 63) == 0) redm[tid >> 6] = lmax;
    __syncthreads();
    float bmax = fmaxf(fmaxf(redm[0], redm[1]), fmaxf(redm[2], redm[3]));
    float lsum = 0.f;
    #pragma unroll
    for (int i = 0; i < 8; i++) {
        float e = __expf(sc[i] - bmax);
        p_lds[tid + 256 * i] = e;
        lsum += e;
    }
    #pragma unroll
    for (int off = 32; off; off >>= 1) lsum += __shfl_xor(lsum, off);
    if ((tid & 63) == 0) reds[tid >> 6] = lsum;
    __syncthreads();   // also makes p_lds visible block-wide
    float inv = 1.0f / (reds[0] + reds[1] + reds[2] + reds[3]);

    int d = tid & 63, c = tid >> 6;
    const float* vb = Vc + (size_t)bh * S_ * HD_;
    float acc = 0.f;
    for (int s = c * 512; s < c * 512 + 512; s++)
        acc += p_lds[s] * vb[(size_t)s * HD_ + d];
    part[c][d] = acc;
    __syncthreads();
    if (tid < HD_) {
        float yv = (part[0][tid] + part[1][tid] + part[2][tid] + part[3][tid]) * inv;
        y[(size_t)(b * T_ + t) * D_ + h * 64 + tid] = yv;
    }
}

// ---------------- router: logits, top-2, gates ----------------
__global__ __launch_bounds__(64) void k_router(const float* __restrict__ xf,
                                               const float* __restrict__ rw,
                                               const float* __restrict__ rb,
                                               float* __restrict__ gates) {
    int tok = blockIdx.x, lane = threadIdx.x;
    float acc[E_] = {0,0,0,0,0,0,0,0};
    for (int k = lane; k < D_; k += 64) {
        float xv = xf[(size_t)tok * D_ + k];
        const float* wr = rw + (size_t)k * E_;
        #pragma unroll
        for (int e = 0; e < E_; e++) acc[e] += xv * wr[e];
    }
    #pragma unroll
    for (int off = 32; off; off >>= 1) {
        #pragma unroll
        for (int e = 0; e < E_; e++) acc[e] += __shfl_xor(acc[e], off);
    }
    if (lane == 0) {
        float l[E_];
        #pragma unroll
        for (int e = 0; e < E_; e++) l[e] = acc[e] + rb[e];
        int i1 = 0;
        #pragma unroll
        for (int e = 1; e < E_; e++) if (l[e] > l[i1]) i1 = e;
        int i2 = -1;
        #pragma unroll
        for (int e = 0; e < E_; e++) {
            if (e == i1) continue;
            if (i2 < 0 || l[e] > l[i2]) i2 = e;
        }
        float e2 = expf(l[i2] - l[i1]);
        float den = 1.0f + e2;
        float g[E_] = {0,0,0,0,0,0,0,0};
        g[i1] = 1.0f / den;
        g[i2] = e2 / den;
        #pragma unroll
        for (int e = 0; e < E_; e++) gates[(size_t)tok * E_ + e] = g[e];
    }
}

// ---------------- elementwise ----------------
__global__ __launch_bounds__(256) void k_silumul(float* __restrict__ g1,
                                                 const float* __restrict__ g3, int n4) {
    int i = blockIdx.x * 256 + threadIdx.x;
    if (i < n4) {
        float4 a = ((const float4*)g1)[i];
        float4 b = ((const float4*)g3)[i];
        float4 r;
        r.x = a.x / (1.f + __expf(-a.x)) * b.x;
        r.y = a.y / (1.f + __expf(-a.y)) * b.y;
        r.z = a.z / (1.f + __expf(-a.z)) * b.z;
        r.w = a.w / (1.f + __expf(-a.w)) * b.w;
        ((float4*)g1)[i] = r;
    }
}

__global__ __launch_bounds__(256) void k_combine(const float* __restrict__ he,
                                                 const float* __restrict__ gates,
                                                 float* __restrict__ moe,
                                                 int e, int beta, int n4) {
    int i = blockIdx.x * 256 + threadIdx.x;
    if (i < n4) {
        int tok = i >> 8;    // 256 float4 per 1024-dim row
        float g = gates[(size_t)tok * E_ + e];
        float4 v = ((const float4*)he)[i];
        float4 r;
        if (beta) {
            float4 m = ((const float4*)moe)[i];
            r.x = m.x + g * v.x; r.y = m.y + g * v.y;
            r.z = m.z + g * v.z; r.w = m.w + g * v.w;
        } else {
            r.x = g * v.x; r.y = g * v.y; r.z = g * v.z; r.w = g * v.w;
        }
        ((float4*)moe)[i] = r;
    }
}

__global__ __launch_bounds__(256) void k_add(const float* __restrict__ a,
                                             const float* __restrict__ b,
                                             float* __restrict__ o, int n4) {
    int i = blockIdx.x * 256 + threadIdx.x;
    if (i < n4) {
        float4 x = ((const float4*)a)[i];
        float4 y = ((const float4*)b)[i];
        float4 r;
        r.x = x.x + y.x; r.y = x.y + y.y; r.z = x.z + y.z; r.w = x.w + y.w;
        ((float4*)o)[i] = r;
    }
}

// ---------------- host ----------------
extern "C" void kernel_launch(void* const* d_in, const int* in_sizes, int n_in,
                              void* d_out, int out_size, void* d_ws, size_t ws_size,
                              hipStream_t stream) {
    (void)in_sizes; (void)n_in; (void)out_size; (void)ws_size;
    const float* q      = (const float*)d_in[0];
    const float* fc     = (const float*)d_in[3];
    const float* fs     = (const float*)d_in[4];
    const float* k_xl   = (const float*)d_in[5];
    const float* v_xl   = (const float*)d_in[6];
    const float* W_qkv  = (const float*)d_in[7];
    const float* W_proj = (const float*)d_in[8];
    const float* pos    = (const float*)d_in[9];
    const float* anw    = (const float*)d_in[10];
    const float* fnw    = (const float*)d_in[11];
    const float* rw     = (const float*)d_in[12];
    const float* rb     = (const float*)d_in[13];
    const float* w1     = (const float*)d_in[14];
    const float* w2     = (const float*)d_in[15];
    const float* w3     = (const float*)d_in[16];
    const int*   caus   = (const int*)d_in[17];

    float* ws = (float*)d_ws;
    const size_t M1 = 1u << 20;
    float* xn    = ws;             // [0, 2M)
    float* qkv   = ws + 2*M1;      // [2M, 8M)
    float* Kc    = ws + 8*M1;      // [8M, 12M)
    float* Vc    = ws + 12*M1;     // [12M, 16M)
    float* y2d   = ws + 16*M1;     // [16M, 18M)  free after proj GEMM
    float* h     = ws + 18*M1;     // [18M, 20M)
    float* xf    = ws + 20*M1;     // [20M, 22M)
    float* proj  = ws + 22*M1;     // [22M, 24M)  reused as `he` in MoE
    float* he    = proj;
    float* moe   = ws + 24*M1;     // [24M, 26M)
    float* gates = ws + 26*M1;     // 16K
    float* G1    = ws + 2*M1;      // [2M, 10M)   reuses qkv/Kc (free after attn)
    float* G3    = ws + 10*M1;     // [10M, 18M)  reuses Kc/Vc/y2d (free after proj)

    const int n2 = NT * D_;        // 2M
    const int n2v = n2 / 4;
    const int nf = NT * FH_;       // 8M
    const int nfv = nf / 4;

    k_rmsnorm<<<NT, 256, 0, stream>>>(q, anw, xn);

    dim3 gqkv(3 * D_ / 64, NT / 64);
    k_gemm<<<gqkv, 256, 0, stream>>>(xn, W_qkv, qkv, NT, 3 * D_, D_);

    k_rope<<<NT, 256, 0, stream>>>(qkv, fc, fs, k_xl, v_xl, pos, Kc, Vc);

    k_attn<<<B_ * H_ * T_, 256, 0, stream>>>(qkv, Kc, Vc, y2d, caus);

    dim3 gproj(D_ / 64, NT / 64);
    k_gemm<<<gproj, 256, 0, stream>>>(y2d, W_proj, proj, NT, D_, D_);

    k_add<<<(n2v + 255) / 256, 256, 0, stream>>>(xn, proj, h, n2v);

    k_rmsnorm<<<NT, 256, 0, stream>>>(h, fnw, xf);

    k_router<<<NT, 64, 0, stream>>>(xf, rw, rb, gates);

    dim3 gup(FH_ / 64, NT / 64);
    dim3 gdn(D_ / 64, NT / 64);
    for (int e = 0; e < E_; e++) {
        const float* w1e = w1 + (size_t)e * D_ * FH_;
        const float* w3e = w3 + (size_t)e * D_ * FH_;
        const float* w2e = w2 + (size_t)e * FH_ * D_;
        k_gemm<<<gup, 256, 0, stream>>>(xf, w1e, G1, NT, FH_, D_);
        k_gemm<<<gup, 256, 0, stream>>>(xf, w3e, G3, NT, FH_, D_);
        k_silumul<<<(nfv + 255) / 256, 256, 0, stream>>>(G1, G3, nfv);
        k_gemm<<<gdn, 256, 0, stream>>>(G1, w2e, he, NT, D_, FH_);
        k_combine<<<(n2v + 255) / 256, 256, 0, stream>>>(he, gates, moe, e, e > 0, n2v);
    }

    k_add<<<(n2v + 255) / 256, 256, 0, stream>>>(h, moe, (float*)d_out, n2v);
}

// Round 6
// 2084.069 us; speedup vs baseline: 2.7441x; 2.7441x over previous
//
#include <hip/hip_runtime.h>
#include <hip/hip_bf16.h>

typedef __attribute__((ext_vector_type(8))) short short8;
typedef __attribute__((ext_vector_type(4))) float f32x4;

#define B_  2
#define T_  1024
#define D_  1024
#define H_  16
#define HD_ 64
#define E_  8
#define FH_ 4096
#define NT  (B_*T_)   // 2048 tokens
#define S_  (2*T_)    // 2048 concat KV length

// ---------------- RMSNorm ----------------
__global__ __launch_bounds__(256) void k_rmsnorm(const float* __restrict__ x,
                                                 const float* __restrict__ w,
                                                 float* __restrict__ o) {
    int row = blockIdx.x, tid = threadIdx.x;
    const float4* x4 = (const float4*)(x + (size_t)row * D_);
    float4 v = x4[tid];
    float ss = v.x*v.x + v.y*v.y + v.z*v.z + v.w*v.w;
    #pragma unroll
    for (int off = 32; off; off >>= 1) ss += __shfl_xor(ss, off);
    __shared__ float wsum[4];
    if ((tid & 63) == 0) wsum[tid >> 6] = ss;
    __syncthreads();
    float tot = wsum[0] + wsum[1] + wsum[2] + wsum[3];
    float scale = rsqrtf(tot * (1.0f / D_) + 1e-6f);
    float4 wv = ((const float4*)w)[tid];
    float4 r;
    r.x = v.x * scale * wv.x; r.y = v.y * scale * wv.y;
    r.z = v.z * scale * wv.z; r.w = v.w * scale * wv.w;
    ((float4*)(o + (size_t)row * D_))[tid] = r;
}

// ---------------- dense bf16 MFMA GEMM: C = A[M,K] * B[K,N], 64x64 tile ----------------
__global__ __launch_bounds__(256) void k_gemm(const float* __restrict__ A,
                                              const float* __restrict__ B,
                                              float* __restrict__ C,
                                              int M, int N, int K) {
    __shared__ __align__(16) __hip_bfloat16 As[64][32];
    __shared__ __align__(16) __hip_bfloat16 Bs[64][32];
    const int tid  = threadIdx.x;
    const int m0   = blockIdx.y << 6, n0 = blockIdx.x << 6;
    const int lane = tid & 63, wid = tid >> 6;
    const int wr   = wid >> 1, wc = wid & 1;
    const int fr   = lane & 15, fk = (lane >> 4) << 3;
    f32x4 acc00 = {0.f,0.f,0.f,0.f};
    f32x4 acc01 = acc00, acc10 = acc00, acc11 = acc00;
    const int arow = tid >> 2, ak0 = (tid & 3) << 3;
    const int bk   = tid >> 3, bn0 = (tid & 7) << 3;

    for (int kk = 0; kk < K; kk += 32) {
        const float* ap = A + (size_t)(m0 + arow) * K + kk + ak0;
        float4 a0v = *(const float4*)ap;
        float4 a1v = *(const float4*)(ap + 4);
        const float* bp = B + (size_t)(kk + bk) * N + n0 + bn0;
        float4 b0v = *(const float4*)bp;
        float4 b1v = *(const float4*)(bp + 4);
        __hip_bfloat16* ad = &As[arow][ak0];
        ad[0] = __float2bfloat16(a0v.x); ad[1] = __float2bfloat16(a0v.y);
        ad[2] = __float2bfloat16(a0v.z); ad[3] = __float2bfloat16(a0v.w);
        ad[4] = __float2bfloat16(a1v.x); ad[5] = __float2bfloat16(a1v.y);
        ad[6] = __float2bfloat16(a1v.z); ad[7] = __float2bfloat16(a1v.w);
        Bs[bn0+0][bk] = __float2bfloat16(b0v.x); Bs[bn0+1][bk] = __float2bfloat16(b0v.y);
        Bs[bn0+2][bk] = __float2bfloat16(b0v.z); Bs[bn0+3][bk] = __float2bfloat16(b0v.w);
        Bs[bn0+4][bk] = __float2bfloat16(b1v.x); Bs[bn0+5][bk] = __float2bfloat16(b1v.y);
        Bs[bn0+6][bk] = __float2bfloat16(b1v.z); Bs[bn0+7][bk] = __float2bfloat16(b1v.w);
        __syncthreads();
        short8 a0 = *(const short8*)&As[(wr<<5) +      fr][fk];
        short8 a1 = *(const short8*)&As[(wr<<5) + 16 + fr][fk];
        short8 b0 = *(const short8*)&Bs[(wc<<5) +      fr][fk];
        short8 b1 = *(const short8*)&Bs[(wc<<5) + 16 + fr][fk];
        acc00 = __builtin_amdgcn_mfma_f32_16x16x32_bf16(a0, b0, acc00, 0, 0, 0);
        acc01 = __builtin_amdgcn_mfma_f32_16x16x32_bf16(a0, b1, acc01, 0, 0, 0);
        acc10 = __builtin_amdgcn_mfma_f32_16x16x32_bf16(a1, b0, acc10, 0, 0, 0);
        acc11 = __builtin_amdgcn_mfma_f32_16x16x32_bf16(a1, b1, acc11, 0, 0, 0);
        __syncthreads();
    }
    const int fq = lane >> 4;
    const int crow = m0 + (wr << 5) + (fq << 2);
    const int ccol = n0 + (wc << 5) + fr;
    #pragma unroll
    for (int r = 0; r < 4; r++) {
        C[(size_t)(crow +      r) * N + ccol     ] = acc00[r];
        C[(size_t)(crow +      r) * N + ccol + 16] = acc01[r];
        C[(size_t)(crow + 16 + r) * N + ccol     ] = acc10[r];
        C[(size_t)(crow + 16 + r) * N + ccol + 16] = acc11[r];
    }
}

// ---------------- gather MoE GEMM with fused epilogues ----------------
// EPI 0: C[(m0+r)*N+c] = acc                       (w1: A=xf gathered)
// EPI 1: C[idx] = silu(C[idx]) * acc               (w3: A=xf gathered, rmw G1)
// EPI 2: moe[tok*D+c] += gate * acc                (w2: A=G1 compact rows)
template<int EPI>
__global__ __launch_bounds__(256) void k_moe_gemm(const float* __restrict__ A,
                                                  const float* __restrict__ Bw,
                                                  float* __restrict__ C,
                                                  const int* __restrict__ list,
                                                  const int* __restrict__ counts,
                                                  int eidx,
                                                  const float* __restrict__ gates,
                                                  float* __restrict__ moe,
                                                  int N, int K) {
    const int cnt = counts[eidx];
    const int m0 = blockIdx.y << 6;
    if (m0 >= cnt) return;
    const int n0 = blockIdx.x << 6;
    __shared__ __align__(16) __hip_bfloat16 As[64][32];
    __shared__ __align__(16) __hip_bfloat16 Bs[64][32];
    const int tid  = threadIdx.x;
    const int lane = tid & 63, wid = tid >> 6;
    const int wr   = wid >> 1, wc = wid & 1;
    const int fr   = lane & 15, fk = (lane >> 4) << 3;
    f32x4 acc00 = {0.f,0.f,0.f,0.f};
    f32x4 acc01 = acc00, acc10 = acc00, acc11 = acc00;
    const int arow = tid >> 2, ak0 = (tid & 3) << 3;
    const int bk   = tid >> 3, bn0 = (tid & 7) << 3;

    int grow;
    if (EPI < 2) grow = (m0 + arow < cnt) ? list[eidx * NT + m0 + arow]
                                          : list[eidx * NT + m0];
    else         grow = m0 + arow;
    const float* abase = A + (size_t)grow * K;

    for (int kk = 0; kk < K; kk += 32) {
        const float* ap = abase + kk + ak0;
        float4 a0v = *(const float4*)ap;
        float4 a1v = *(const float4*)(ap + 4);
        const float* bp = Bw + (size_t)(kk + bk) * N + n0 + bn0;
        float4 b0v = *(const float4*)bp;
        float4 b1v = *(const float4*)(bp + 4);
        __hip_bfloat16* ad = &As[arow][ak0];
        ad[0] = __float2bfloat16(a0v.x); ad[1] = __float2bfloat16(a0v.y);
        ad[2] = __float2bfloat16(a0v.z); ad[3] = __float2bfloat16(a0v.w);
        ad[4] = __float2bfloat16(a1v.x); ad[5] = __float2bfloat16(a1v.y);
        ad[6] = __float2bfloat16(a1v.z); ad[7] = __float2bfloat16(a1v.w);
        Bs[bn0+0][bk] = __float2bfloat16(b0v.x); Bs[bn0+1][bk] = __float2bfloat16(b0v.y);
        Bs[bn0+2][bk] = __float2bfloat16(b0v.z); Bs[bn0+3][bk] = __float2bfloat16(b0v.w);
        Bs[bn0+4][bk] = __float2bfloat16(b1v.x); Bs[bn0+5][bk] = __float2bfloat16(b1v.y);
        Bs[bn0+6][bk] = __float2bfloat16(b1v.z); Bs[bn0+7][bk] = __float2bfloat16(b1v.w);
        __syncthreads();
        short8 a0 = *(const short8*)&As[(wr<<5) +      fr][fk];
        short8 a1 = *(const short8*)&As[(wr<<5) + 16 + fr][fk];
        short8 b0 = *(const short8*)&Bs[(wc<<5) +      fr][fk];
        short8 b1 = *(const short8*)&Bs[(wc<<5) + 16 + fr][fk];
        acc00 = __builtin_amdgcn_mfma_f32_16x16x32_bf16(a0, b0, acc00, 0, 0, 0);
        acc01 = __builtin_amdgcn_mfma_f32_16x16x32_bf16(a0, b1, acc01, 0, 0, 0);
        acc10 = __builtin_amdgcn_mfma_f32_16x16x32_bf16(a1, b0, acc10, 0, 0, 0);
        acc11 = __builtin_amdgcn_mfma_f32_16x16x32_bf16(a1, b1, acc11, 0, 0, 0);
        __syncthreads();
    }

    const int fq = lane >> 4;
    auto epi = [&](int rl, int cl, float val) {
        if (EPI == 0) {
            C[(size_t)(m0 + rl) * N + n0 + cl] = val;
        } else if (EPI == 1) {
            size_t idx = (size_t)(m0 + rl) * N + n0 + cl;
            float g1 = C[idx];
            C[idx] = g1 / (1.f + __expf(-g1)) * val;
        } else {
            int row = m0 + rl;
            if (row < cnt) {
                int tok = list[eidx * NT + row];
                float gv = gates[(size_t)tok * E_ + eidx];
                moe[(size_t)tok * D_ + n0 + cl] += gv * val;
            }
        }
    };
    #pragma unroll
    for (int r = 0; r < 4; r++) {
        int r0 = (wr << 5) + (fq << 2) + r, r1 = r0 + 16;
        int c0 = (wc << 5) + fr, c1 = c0 + 16;
        epi(r0, c0, acc00[r]); epi(r0, c1, acc01[r]);
        epi(r1, c0, acc10[r]); epi(r1, c1, acc11[r]);
    }
}

// ---------------- RoPE + build concat K/V (bf16) ----------------
__global__ __launch_bounds__(256) void k_rope(float* __restrict__ qkv,
                                              const float* __restrict__ fc,
                                              const float* __restrict__ fs,
                                              const float* __restrict__ k_xl,
                                              const float* __restrict__ v_xl,
                                              const float* __restrict__ pos,
                                              __hip_bfloat16* __restrict__ Kc,
                                              __hip_bfloat16* __restrict__ Vc) {
    int bt = blockIdx.x;
    int b = bt >> 10, t = bt & (T_ - 1);
    int tid = threadIdx.x;
    for (int p = tid; p < D_ / 2; p += 256) {
        int h = p >> 5, i = p & 31;
        float c = fc[t * 32 + i], s = fs[t * 32 + i];
        size_t qoff = (size_t)bt * 3072 + h * 64 + 2 * i;
        float qr = qkv[qoff], qi = qkv[qoff + 1];
        qkv[qoff]     = qr * c - qi * s;
        qkv[qoff + 1] = qr * s + qi * c;
        float kr = qkv[qoff + 1024], ki = qkv[qoff + 1025];
        size_t koff = ((size_t)(b * H_ + h) * S_ + T_ + t) * HD_ + 2 * i;
        Kc[koff]     = __float2bfloat16(kr * c - ki * s);
        Kc[koff + 1] = __float2bfloat16(kr * s + ki * c);
        Vc[koff]     = __float2bfloat16(qkv[qoff + 2048]);
        Vc[koff + 1] = __float2bfloat16(qkv[qoff + 2049]);
    }
    for (int d = tid; d < D_; d += 256) {
        int h = d >> 6, dd = d & 63;
        size_t src = (size_t)bt * D_ + d;
        size_t dst = ((size_t)(b * H_ + h) * S_ + t) * HD_ + dd;
        Kc[dst] = __float2bfloat16(k_xl[src] + pos[(size_t)t * D_ + d]);
        Vc[dst] = __float2bfloat16(v_xl[src]);
    }
}

// ---------------- MFMA flash attention ----------------
// block = (qtile of 64 rows, bh). 4 waves, wave w owns q-strip w*16..w*16+15.
// S^T = K * Q^T  (col of C = q = lane&15 -> wave-local online softmax)
// O^T = V^T * P^T (col of C = q = lane&15 -> per-lane rescale)
__global__ __launch_bounds__(256) void k_attn_mfma(const float* __restrict__ qkv,
                                                   const __hip_bfloat16* __restrict__ Kc,
                                                   const __hip_bfloat16* __restrict__ Vc,
                                                   float* __restrict__ y,
                                                   const int* __restrict__ pcausal) {
    __shared__ __align__(16) __hip_bfloat16 Qs[64][72];
    __shared__ __align__(16) __hip_bfloat16 Ks[64][72];
    __shared__ __align__(16) __hip_bfloat16 VsT[64][72];   // [d][s]
    __shared__ __align__(16) __hip_bfloat16 Ps[4][16][72]; // per-wave [q][s]
    const int qt = blockIdx.x, bh = blockIdx.y;
    const int b = bh >> 4, h = bh & 15;
    const int tid = threadIdx.x, lane = tid & 63, wid = tid >> 6;
    const int fr = lane & 15, g = lane >> 4, fk = g << 3;
    const int causal = pcausal[0];
    const int qbase = qt << 6;

    {   // stage Q (f32 -> bf16), once
        int qrow = tid >> 2, dk = (tid & 3) << 4;
        const float* src = qkv + (size_t)(b * T_ + qbase + qrow) * 3072 + h * 64 + dk;
        __hip_bfloat16* dst = &Qs[qrow][dk];
        #pragma unroll
        for (int i = 0; i < 16; i += 4) {
            float4 v = *(const float4*)(src + i);
            dst[i]   = __float2bfloat16(v.x); dst[i+1] = __float2bfloat16(v.y);
            dst[i+2] = __float2bfloat16(v.z); dst[i+3] = __float2bfloat16(v.w);
        }
    }

    const __hip_bfloat16* Kb = Kc + (size_t)bh * S_ * HD_;
    const __hip_bfloat16* Vb = Vc + (size_t)bh * S_ * HD_;
    const int krow = tid >> 2, kdk = (tid & 3) << 4;
    const int vs = tid & 63, vd0 = (tid >> 6) << 4;
    const int q_t = qbase + (wid << 4) + fr;   // query index in [0,T)

    float m_run = -1e30f, l_run = 0.f;
    f32x4 o0 = {0.f,0.f,0.f,0.f}, o1 = o0, o2 = o0, o3 = o0;

    for (int kt = 0; kt < 32; ++kt) {
        const int s0 = kt << 6;
        {   // stage K tile [s][d]
            const __hip_bfloat16* src = Kb + (size_t)(s0 + krow) * HD_ + kdk;
            short8 u0 = *(const short8*)src;
            short8 u1 = *(const short8*)(src + 8);
            *(short8*)&Ks[krow][kdk]     = u0;
            *(short8*)&Ks[krow][kdk + 8] = u1;
        }
        {   // stage V^T tile [d][s]
            const __hip_bfloat16* src = Vb + (size_t)(s0 + vs) * HD_ + vd0;
            short8 u0 = *(const short8*)src;
            short8 u1 = *(const short8*)(src + 8);
            #pragma unroll
            for (int i = 0; i < 8; i++) VsT[vd0 + i][vs]     = ((const __hip_bfloat16*)&u0)[i];
            #pragma unroll
            for (int i = 0; i < 8; i++) VsT[vd0 + 8 + i][vs] = ((const __hip_bfloat16*)&u1)[i];
        }
        __syncthreads();

        // S^T strips: 4 m-steps of 16 s-rows
        f32x4 st[4];
        #pragma unroll
        for (int ms = 0; ms < 4; ++ms) {
            f32x4 acc = {0.f,0.f,0.f,0.f};
            #pragma unroll
            for (int dk = 0; dk < 64; dk += 32) {
                short8 kf = *(const short8*)&Ks[(ms << 4) + fr][dk + fk];
                short8 qf = *(const short8*)&Qs[(wid << 4) + fr][dk + fk];
                acc = __builtin_amdgcn_mfma_f32_16x16x32_bf16(kf, qf, acc, 0, 0, 0);
            }
            st[ms] = acc;
        }

        float pmax = -1e30f;
        #pragma unroll
        for (int ms = 0; ms < 4; ++ms) {
            #pragma unroll
            for (int r = 0; r < 4; ++r) {
                float v = st[ms][r] * 0.125f;
                if (causal) {
                    int s_g = s0 + (ms << 4) + (g << 2) + r;
                    if (s_g > q_t) v = -1e30f;
                }
                st[ms][r] = v;
                pmax = fmaxf(pmax, v);
            }
        }
        pmax = fmaxf(pmax, __shfl_xor(pmax, 16));
        pmax = fmaxf(pmax, __shfl_xor(pmax, 32));

        float mnew = fmaxf(m_run, pmax);
        float scl = __expf(m_run - mnew);
        float tsum = 0.f;
        #pragma unroll
        for (int ms = 0; ms < 4; ++ms) {
            #pragma unroll
            for (int r = 0; r < 4; ++r) {
                float p = __expf(st[ms][r] - mnew);
                tsum += p;
                Ps[wid][fr][(ms << 4) + (g << 2) + r] = __float2bfloat16(p);
            }
        }
        tsum += __shfl_xor(tsum, 16);
        tsum += __shfl_xor(tsum, 32);
        l_run = l_run * scl + tsum;
        m_run = mnew;
        o0 *= scl; o1 *= scl; o2 *= scl; o3 *= scl;

        // LDS write->read ordering for the cross-lane Ps consumption below.
        __syncthreads();

        // O^T strips: 4 d-steps
        #pragma unroll
        for (int ks = 0; ks < 64; ks += 32) {
            short8 pf = *(const short8*)&Ps[wid][fr][ks + fk];
            short8 v0 = *(const short8*)&VsT[ 0 + fr][ks + fk];
            short8 v1 = *(const short8*)&VsT[16 + fr][ks + fk];
            short8 v2 = *(const short8*)&VsT[32 + fr][ks + fk];
            short8 v3 = *(const short8*)&VsT[48 + fr][ks + fk];
            o0 = __builtin_amdgcn_mfma_f32_16x16x32_bf16(v0, pf, o0, 0, 0, 0);
            o1 = __builtin_amdgcn_mfma_f32_16x16x32_bf16(v1, pf, o1, 0, 0, 0);
            o2 = __builtin_amdgcn_mfma_f32_16x16x32_bf16(v2, pf, o2, 0, 0, 0);
            o3 = __builtin_amdgcn_mfma_f32_16x16x32_bf16(v3, pf, o3, 0, 0, 0);
        }
        __syncthreads();
    }

    float invl = (l_run > 0.f) ? (1.0f / l_run) : 0.f;
    float* yb = y + (size_t)(b * T_ + qbase + (wid << 4) + fr) * D_ + h * HD_;
    #pragma unroll
    for (int r = 0; r < 4; ++r) {
        yb[ 0 + (g << 2) + r] = o0[r] * invl;
        yb[16 + (g << 2) + r] = o1[r] * invl;
        yb[32 + (g << 2) + r] = o2[r] * invl;
        yb[48 + (g << 2) + r] = o3[r] * invl;
    }
}

// ---------------- router: logits, top-2, gates + expert lists ----------------
__global__ __launch_bounds__(64) void k_router(const float* __restrict__ xf,
                                               const float* __restrict__ rw,
                                               const float* __restrict__ rb,
                                               float* __restrict__ gates,
                                               int* __restrict__ counts,
                                               int* __restrict__ lists) {
    int tok = blockIdx.x, lane = threadIdx.x;
    float acc[E_] = {0,0,0,0,0,0,0,0};
    for (int k = lane; k < D_; k += 64) {
        float xv = xf[(size_t)tok * D_ + k];
        const float* wr = rw + (size_t)k * E_;
        #pragma unroll
        for (int e = 0; e < E_; e++) acc[e] += xv * wr[e];
    }
    #pragma unroll
    for (int off = 32; off; off >>= 1) {
        #pragma unroll
        for (int e = 0; e < E_; e++) acc[e] += __shfl_xor(acc[e], off);
    }
    if (lane == 0) {
        float l[E_];
        #pragma unroll
        for (int e = 0; e < E_; e++) l[e] = acc[e] + rb[e];
        int i1 = 0;
        #pragma unroll
        for (int e = 1; e < E_; e++) if (l[e] > l[i1]) i1 = e;
        int i2 = -1;
        #pragma unroll
        for (int e = 0; e < E_; e++) {
            if (e == i1) continue;
            if (i2 < 0 || l[e] > l[i2]) i2 = e;
        }
        float e2 = expf(l[i2] - l[i1]);
        float den = 1.0f + e2;
        float gv[E_] = {0,0,0,0,0,0,0,0};
        gv[i1] = 1.0f / den;
        gv[i2] = e2 / den;
        #pragma unroll
        for (int e = 0; e < E_; e++) gates[(size_t)tok * E_ + e] = gv[e];
        int p1 = atomicAdd(&counts[i1], 1);
        lists[i1 * NT + p1] = tok;
        int p2 = atomicAdd(&counts[i2], 1);
        lists[i2 * NT + p2] = tok;
    }
}

__global__ __launch_bounds__(256) void k_add(const float* __restrict__ a,
                                             const float* __restrict__ b,
                                             float* __restrict__ o, int n4) {
    int i = blockIdx.x * 256 + threadIdx.x;
    if (i < n4) {
        float4 x = ((const float4*)a)[i];
        float4 y = ((const float4*)b)[i];
        float4 r;
        r.x = x.x + y.x; r.y = x.y + y.y; r.z = x.z + y.z; r.w = x.w + y.w;
        ((float4*)o)[i] = r;
    }
}

// ---------------- host ----------------
extern "C" void kernel_launch(void* const* d_in, const int* in_sizes, int n_in,
                              void* d_out, int out_size, void* d_ws, size_t ws_size,
                              hipStream_t stream) {
    (void)in_sizes; (void)n_in; (void)out_size; (void)ws_size;
    const float* q      = (const float*)d_in[0];
    const float* fc     = (const float*)d_in[3];
    const float* fs     = (const float*)d_in[4];
    const float* k_xl   = (const float*)d_in[5];
    const float* v_xl   = (const float*)d_in[6];
    const float* W_qkv  = (const float*)d_in[7];
    const float* W_proj = (const float*)d_in[8];
    const float* pos    = (const float*)d_in[9];
    const float* anw    = (const float*)d_in[10];
    const float* fnw    = (const float*)d_in[11];
    const float* rw     = (const float*)d_in[12];
    const float* rb     = (const float*)d_in[13];
    const float* w1     = (const float*)d_in[14];
    const float* w2     = (const float*)d_in[15];
    const float* w3     = (const float*)d_in[16];
    const int*   caus   = (const int*)d_in[17];

    float* ws = (float*)d_ws;
    const size_t M1 = 1u << 20;
    // Workspace map (Kc/Vc are 4M bf16 = 2M floats EACH):
    float* xn    = ws;                        // [ 0M, 2M)
    float* qkv   = ws + 2*M1;                 // [ 2M, 8M)   free after attn
    __hip_bfloat16* Kc = (__hip_bfloat16*)(ws +  8*M1);  // [ 8M,10M)  free after attn
    __hip_bfloat16* Vc = (__hip_bfloat16*)(ws + 10*M1);  // [10M,12M)  free after attn
    float* y2d   = ws + 12*M1;                // [12M,14M)  free after proj
    float* h     = ws + 14*M1;                // [14M,16M)
    float* xf    = ws + 16*M1;                // [16M,18M)
    float* proj  = ws + 18*M1;                // [18M,20M)  free after k_add(h)
    float* moe   = ws + 20*M1;                // [20M,22M)
    float* gates = ws + 22*M1;                // 16384 floats
    int*   counts= (int*)(ws + 22*M1 + 16384);
    int*   lists = counts + 8;                // 8*2048 ints
    float* G1c   = ws + 2*M1;                 // [2M,10M)  reuses qkv+Kc (free after attn)

    const int n2v = NT * D_ / 4;

    hipMemsetAsync(counts, 0, 8 * sizeof(int), stream);
    hipMemsetAsync(moe, 0, (size_t)NT * D_ * sizeof(float), stream);

    k_rmsnorm<<<NT, 256, 0, stream>>>(q, anw, xn);

    dim3 gqkv(3 * D_ / 64, NT / 64);
    k_gemm<<<gqkv, 256, 0, stream>>>(xn, W_qkv, qkv, NT, 3 * D_, D_);

    k_rope<<<NT, 256, 0, stream>>>(qkv, fc, fs, k_xl, v_xl, pos, Kc, Vc);

    dim3 gattn(T_ / 64, B_ * H_);
    k_attn_mfma<<<gattn, 256, 0, stream>>>(qkv, Kc, Vc, y2d, caus);

    dim3 gproj(D_ / 64, NT / 64);
    k_gemm<<<gproj, 256, 0, stream>>>(y2d, W_proj, proj, NT, D_, D_);

    k_add<<<(n2v + 255) / 256, 256, 0, stream>>>(xn, proj, h, n2v);

    k_rmsnorm<<<NT, 256, 0, stream>>>(h, fnw, xf);

    k_router<<<NT, 64, 0, stream>>>(xf, rw, rb, gates, counts, lists);

    dim3 gup(FH_ / 64, NT / 64);
    dim3 gdn(D_ / 64, NT / 64);
    for (int e = 0; e < E_; e++) {
        const float* w1e = w1 + (size_t)e * D_ * FH_;
        const float* w3e = w3 + (size_t)e * D_ * FH_;
        const float* w2e = w2 + (size_t)e * FH_ * D_;
        k_moe_gemm<0><<<gup, 256, 0, stream>>>(xf, w1e, G1c, lists, counts, e, gates, moe, FH_, D_);
        k_moe_gemm<1><<<gup, 256, 0, stream>>>(xf, w3e, G1c, lists, counts, e, gates, moe, FH_, D_);
        k_moe_gemm<2><<<gdn, 256, 0, stream>>>(G1c, w2e, nullptr, lists, counts, e, gates, moe, D_, FH_);
    }

    k_add<<<(n2v + 255) / 256, 256, 0, stream>>>(h, moe, (float*)d_out, n2v);
}

// Round 8
// 873.039 us; speedup vs baseline: 6.5505x; 2.3871x over previous
//
#include <hip/hip_runtime.h>
#include <hip/hip_bf16.h>

typedef __attribute__((ext_vector_type(8))) short short8;
typedef __attribute__((ext_vector_type(4))) float f32x4;

#define B_  2
#define T_  1024
#define D_  1024
#define H_  16
#define HD_ 64
#define E_  8
#define FH_ 4096
#define NT  (B_*T_)   // 2048 tokens
#define S_  (2*T_)    // 2048 concat KV length
#define YMAX 72       // max padded row-blocks across experts: 4096/64 + 8
#define LP  40        // padded LDS row length (elems); 80B rows, 16B-aligned

static __device__ inline short bf16b(float x) {
    __hip_bfloat16 t = __float2bfloat16(x);
    short s; __builtin_memcpy(&s, &t, 2); return s;
}

// ---------------- RMSNorm ----------------
__global__ __launch_bounds__(256) void k_rmsnorm(const float* __restrict__ x,
                                                 const float* __restrict__ w,
                                                 float* __restrict__ o) {
    int row = blockIdx.x, tid = threadIdx.x;
    const float4* x4 = (const float4*)(x + (size_t)row * D_);
    float4 v = x4[tid];
    float ss = v.x*v.x + v.y*v.y + v.z*v.z + v.w*v.w;
    #pragma unroll
    for (int off = 32; off; off >>= 1) ss += __shfl_xor(ss, off);
    __shared__ float wsum[4];
    if ((tid & 63) == 0) wsum[tid >> 6] = ss;
    __syncthreads();
    float tot = wsum[0] + wsum[1] + wsum[2] + wsum[3];
    float scale = rsqrtf(tot * (1.0f / D_) + 1e-6f);
    float4 wv = ((const float4*)w)[tid];
    float4 r;
    r.x = v.x * scale * wv.x; r.y = v.y * scale * wv.y;
    r.z = v.z * scale * wv.z; r.w = v.w * scale * wv.w;
    ((float4*)(o + (size_t)row * D_))[tid] = r;
}

// ---------------- dense bf16 MFMA GEMM: C = A[M,K] * B[K,N], 64x64 tile ----------------
// Swizzled Bs: logical k-chunk cb of row n stored at phys chunk cb ^ ((n>>3)&3).
__global__ __launch_bounds__(256) void k_gemm(const float* __restrict__ A,
                                              const float* __restrict__ B,
                                              float* __restrict__ C,
                                              int M, int N, int K) {
    __shared__ __align__(16) __hip_bfloat16 As[64][LP];
    __shared__ __align__(16) __hip_bfloat16 Bs[64][LP];
    const int tid  = threadIdx.x;
    const int m0   = blockIdx.y << 6, n0 = blockIdx.x << 6;
    const int lane = tid & 63, wid = tid >> 6;
    const int wr   = wid >> 1, wc = wid & 1;
    const int fr   = lane & 15, g = lane >> 4, fk = g << 3;
    const int arow = tid >> 2, ak0 = (tid & 3) << 3;
    const int bk   = tid >> 3, bn0 = (tid & 7) << 3;
    const int cb   = bk >> 3,  bk7 = bk & 7;
    f32x4 acc00 = {0.f,0.f,0.f,0.f};
    f32x4 acc01 = acc00, acc10 = acc00, acc11 = acc00;
    const int nb0 = (wc << 5) + fr, nb1 = nb0 + 16;
    const int pb0 = (g ^ ((nb0 >> 3) & 3)) << 3;
    const int pb1 = (g ^ ((nb1 >> 3) & 3)) << 3;

    for (int kk = 0; kk < K; kk += 32) {
        const float* ap = A + (size_t)(m0 + arow) * K + kk + ak0;
        float4 a0v = *(const float4*)ap;
        float4 a1v = *(const float4*)(ap + 4);
        const float* bp = B + (size_t)(kk + bk) * N + n0 + bn0;
        float4 b0v = *(const float4*)bp;
        float4 b1v = *(const float4*)(bp + 4);
        short8 at;
        at[0]=bf16b(a0v.x); at[1]=bf16b(a0v.y); at[2]=bf16b(a0v.z); at[3]=bf16b(a0v.w);
        at[4]=bf16b(a1v.x); at[5]=bf16b(a1v.y); at[6]=bf16b(a1v.z); at[7]=bf16b(a1v.w);
        *(short8*)&As[arow][ak0] = at;
        float bv[8] = {b0v.x,b0v.y,b0v.z,b0v.w,b1v.x,b1v.y,b1v.z,b1v.w};
        #pragma unroll
        for (int j = 0; j < 8; j++) {
            int n  = bn0 + j;
            int kp = ((cb ^ ((n >> 3) & 3)) << 3) | bk7;
            Bs[n][kp] = __float2bfloat16(bv[j]);
        }
        __syncthreads();
        short8 a0 = *(const short8*)&As[(wr<<5) +      fr][fk];
        short8 a1 = *(const short8*)&As[(wr<<5) + 16 + fr][fk];
        short8 b0 = *(const short8*)&Bs[nb0][pb0];
        short8 b1 = *(const short8*)&Bs[nb1][pb1];
        acc00 = __builtin_amdgcn_mfma_f32_16x16x32_bf16(a0, b0, acc00, 0, 0, 0);
        acc01 = __builtin_amdgcn_mfma_f32_16x16x32_bf16(a0, b1, acc01, 0, 0, 0);
        acc10 = __builtin_amdgcn_mfma_f32_16x16x32_bf16(a1, b0, acc10, 0, 0, 0);
        acc11 = __builtin_amdgcn_mfma_f32_16x16x32_bf16(a1, b1, acc11, 0, 0, 0);
        __syncthreads();
    }
    const int fq = lane >> 4;
    const int crow = m0 + (wr << 5) + (fq << 2);
    const int ccol = n0 + (wc << 5) + fr;
    #pragma unroll
    for (int r = 0; r < 4; r++) {
        C[(size_t)(crow +      r) * N + ccol     ] = acc00[r];
        C[(size_t)(crow +      r) * N + ccol + 16] = acc01[r];
        C[(size_t)(crow + 16 + r) * N + ccol     ] = acc10[r];
        C[(size_t)(crow + 16 + r) * N + ccol + 16] = acc11[r];
    }
}

// ---------------- y-block table: maps padded row-blocks -> (expert, local base) ----------------
__global__ __launch_bounds__(64) void k_ytab(const int* __restrict__ counts,
                                             int* __restrict__ yexp,
                                             int* __restrict__ yrow0) {
    if (threadIdx.x == 0) {
        int y = 0;
        for (int e = 0; e < E_; e++) {
            int nb = (counts[e] + 63) >> 6;
            for (int i = 0; i < nb; i++) { yexp[y] = e; yrow0[y] = i << 6; y++; }
        }
        for (; y < YMAX; y++) { yexp[y] = -1; yrow0[y] = 0; }
    }
}

// ---------------- fused MoE up: G = silu(xf*w1[e]) * (xf*w3[e]) -> bf16 ----------------
// grid (FH/64, YMAX); G row = blockIdx.y*64 + r (padded-global row index)
__global__ __launch_bounds__(256) void k_moe_up(const float* __restrict__ xf,
                                                const float* __restrict__ w1,
                                                const float* __restrict__ w3,
                                                __hip_bfloat16* __restrict__ G,
                                                const int* __restrict__ lists,
                                                const int* __restrict__ counts,
                                                const int* __restrict__ yexp,
                                                const int* __restrict__ yrow0) {
    const int e = yexp[blockIdx.y];
    if (e < 0) return;
    const int lbase = yrow0[blockIdx.y];
    const int cnt = counts[e];
    const int n0 = blockIdx.x << 6;
    __shared__ __align__(16) __hip_bfloat16 As[64][LP];
    __shared__ __align__(16) __hip_bfloat16 Bs1[64][LP];
    __shared__ __align__(16) __hip_bfloat16 Bs3[64][LP];
    const int tid  = threadIdx.x;
    const int lane = tid & 63, wid = tid >> 6;
    const int wr   = wid >> 1, wc = wid & 1;
    const int fr   = lane & 15, g = lane >> 4, fk = g << 3;
    const int arow = tid >> 2, ak0 = (tid & 3) << 3;
    const int bk   = tid >> 3, bn0 = (tid & 7) << 3;
    const int cb   = bk >> 3,  bk7 = bk & 7;
    f32x4 c100 = {0.f,0.f,0.f,0.f};
    f32x4 c101 = c100, c110 = c100, c111 = c100;
    f32x4 c300 = c100, c301 = c100, c310 = c100, c311 = c100;
    const int nb0 = (wc << 5) + fr, nb1 = nb0 + 16;
    const int pb0 = (g ^ ((nb0 >> 3) & 3)) << 3;
    const int pb1 = (g ^ ((nb1 >> 3) & 3)) << 3;

    int lrow = lbase + arow;
    int tok  = lists[e * NT + (lrow < cnt ? lrow : cnt - 1)];
    const float* abase = xf + (size_t)tok * D_;
    const float* B1 = w1 + (size_t)e * D_ * FH_;
    const float* B3 = w3 + (size_t)e * D_ * FH_;

    for (int kk = 0; kk < D_; kk += 32) {
        const float* ap = abase + kk + ak0;
        float4 a0v = *(const float4*)ap;
        float4 a1v = *(const float4*)(ap + 4);
        size_t boff = (size_t)(kk + bk) * FH_ + n0 + bn0;
        const float* bp1 = B1 + boff;
        const float* bp3 = B3 + boff;
        float4 p0 = *(const float4*)bp1, p1 = *(const float4*)(bp1 + 4);
        float4 q0 = *(const float4*)bp3, q1 = *(const float4*)(bp3 + 4);
        short8 at;
        at[0]=bf16b(a0v.x); at[1]=bf16b(a0v.y); at[2]=bf16b(a0v.z); at[3]=bf16b(a0v.w);
        at[4]=bf16b(a1v.x); at[5]=bf16b(a1v.y); at[6]=bf16b(a1v.z); at[7]=bf16b(a1v.w);
        *(short8*)&As[arow][ak0] = at;
        float pv[8] = {p0.x,p0.y,p0.z,p0.w,p1.x,p1.y,p1.z,p1.w};
        float qv[8] = {q0.x,q0.y,q0.z,q0.w,q1.x,q1.y,q1.z,q1.w};
        #pragma unroll
        for (int j = 0; j < 8; j++) {
            int n  = bn0 + j;
            int kp = ((cb ^ ((n >> 3) & 3)) << 3) | bk7;
            Bs1[n][kp] = __float2bfloat16(pv[j]);
            Bs3[n][kp] = __float2bfloat16(qv[j]);
        }
        __syncthreads();
        short8 a0 = *(const short8*)&As[(wr<<5) +      fr][fk];
        short8 a1 = *(const short8*)&As[(wr<<5) + 16 + fr][fk];
        short8 u0 = *(const short8*)&Bs1[nb0][pb0];
        short8 u1 = *(const short8*)&Bs1[nb1][pb1];
        short8 v0 = *(const short8*)&Bs3[nb0][pb0];
        short8 v1 = *(const short8*)&Bs3[nb1][pb1];
        c100 = __builtin_amdgcn_mfma_f32_16x16x32_bf16(a0, u0, c100, 0, 0, 0);
        c101 = __builtin_amdgcn_mfma_f32_16x16x32_bf16(a0, u1, c101, 0, 0, 0);
        c110 = __builtin_amdgcn_mfma_f32_16x16x32_bf16(a1, u0, c110, 0, 0, 0);
        c111 = __builtin_amdgcn_mfma_f32_16x16x32_bf16(a1, u1, c111, 0, 0, 0);
        c300 = __builtin_amdgcn_mfma_f32_16x16x32_bf16(a0, v0, c300, 0, 0, 0);
        c301 = __builtin_amdgcn_mfma_f32_16x16x32_bf16(a0, v1, c301, 0, 0, 0);
        c310 = __builtin_amdgcn_mfma_f32_16x16x32_bf16(a1, v0, c310, 0, 0, 0);
        c311 = __builtin_amdgcn_mfma_f32_16x16x32_bf16(a1, v1, c311, 0, 0, 0);
        __syncthreads();
    }
    const int fq = lane >> 4;
    const size_t gr0 = (size_t)blockIdx.y * 64;
    auto wrG = [&](int rr, int cc, float a1v, float a3v) {
        float gv = a1v / (1.f + __expf(-a1v)) * a3v;
        G[(gr0 + rr) * FH_ + n0 + cc] = __float2bfloat16(gv);
    };
    #pragma unroll
    for (int r = 0; r < 4; r++) {
        int r0 = (wr << 5) + (fq << 2) + r, r1 = r0 + 16;
        int c0 = (wc << 5) + fr, c1c = c0 + 16;
        wrG(r0, c0, c100[r], c300[r]); wrG(r0, c1c, c101[r], c301[r]);
        wrG(r1, c0, c110[r], c310[r]); wrG(r1, c1c, c111[r], c311[r]);
    }
}

// ---------------- fused MoE down: moe[tok] += gate * (G * w2[e]) ----------------
// grid (D/64, YMAX); A = G (bf16, padded-global rows), atomic scatter epilogue
__global__ __launch_bounds__(256) void k_moe_dn(const __hip_bfloat16* __restrict__ G,
                                                const float* __restrict__ w2,
                                                float* __restrict__ moe,
                                                const int* __restrict__ lists,
                                                const int* __restrict__ counts,
                                                const int* __restrict__ yexp,
                                                const int* __restrict__ yrow0,
                                                const float* __restrict__ gates) {
    const int e = yexp[blockIdx.y];
    if (e < 0) return;
    const int lbase = yrow0[blockIdx.y];
    const int cnt = counts[e];
    const int n0 = blockIdx.x << 6;
    __shared__ __align__(16) __hip_bfloat16 As[64][LP];
    __shared__ __align__(16) __hip_bfloat16 Bs[64][LP];
    const int tid  = threadIdx.x;
    const int lane = tid & 63, wid = tid >> 6;
    const int wr   = wid >> 1, wc = wid & 1;
    const int fr   = lane & 15, g = lane >> 4, fk = g << 3;
    const int arow = tid >> 2, ak0 = (tid & 3) << 3;
    const int bk   = tid >> 3, bn0 = (tid & 7) << 3;
    const int cb   = bk >> 3,  bk7 = bk & 7;
    f32x4 acc00 = {0.f,0.f,0.f,0.f};
    f32x4 acc01 = acc00, acc10 = acc00, acc11 = acc00;
    const int nb0 = (wc << 5) + fr, nb1 = nb0 + 16;
    const int pb0 = (g ^ ((nb0 >> 3) & 3)) << 3;
    const int pb1 = (g ^ ((nb1 >> 3) & 3)) << 3;

    const __hip_bfloat16* abase = G + ((size_t)blockIdx.y * 64 + arow) * FH_;
    const float* Bw = w2 + (size_t)e * FH_ * D_;

    for (int kk = 0; kk < FH_; kk += 32) {
        *(short8*)&As[arow][ak0] = *(const short8*)(abase + kk + ak0);
        const float* bp = Bw + (size_t)(kk + bk) * D_ + n0 + bn0;
        float4 b0v = *(const float4*)bp;
        float4 b1v = *(const float4*)(bp + 4);
        float bv[8] = {b0v.x,b0v.y,b0v.z,b0v.w,b1v.x,b1v.y,b1v.z,b1v.w};
        #pragma unroll
        for (int j = 0; j < 8; j++) {
            int n  = bn0 + j;
            int kp = ((cb ^ ((n >> 3) & 3)) << 3) | bk7;
            Bs[n][kp] = __float2bfloat16(bv[j]);
        }
        __syncthreads();
        short8 a0 = *(const short8*)&As[(wr<<5) +      fr][fk];
        short8 a1 = *(const short8*)&As[(wr<<5) + 16 + fr][fk];
        short8 b0 = *(const short8*)&Bs[nb0][pb0];
        short8 b1 = *(const short8*)&Bs[nb1][pb1];
        acc00 = __builtin_amdgcn_mfma_f32_16x16x32_bf16(a0, b0, acc00, 0, 0, 0);
        acc01 = __builtin_amdgcn_mfma_f32_16x16x32_bf16(a0, b1, acc01, 0, 0, 0);
        acc10 = __builtin_amdgcn_mfma_f32_16x16x32_bf16(a1, b0, acc10, 0, 0, 0);
        acc11 = __builtin_amdgcn_mfma_f32_16x16x32_bf16(a1, b1, acc11, 0, 0, 0);
        __syncthreads();
    }
    const int fq = lane >> 4;
    auto sc = [&](int rl, int cl, float val) {
        int lrow = lbase + rl;
        if (lrow < cnt) {
            int tok = lists[e * NT + lrow];
            float gv = gates[(size_t)tok * E_ + e];
            atomicAdd(&moe[(size_t)tok * D_ + n0 + cl], gv * val);
        }
    };
    #pragma unroll
    for (int r = 0; r < 4; r++) {
        int r0 = (wr << 5) + (fq << 2) + r, r1 = r0 + 16;
        int c0 = (wc << 5) + fr, c1c = c0 + 16;
        sc(r0, c0, acc00[r]); sc(r0, c1c, acc01[r]);
        sc(r1, c0, acc10[r]); sc(r1, c1c, acc11[r]);
    }
}

// ---------------- RoPE + build concat K/V (bf16) ----------------
__global__ __launch_bounds__(256) void k_rope(float* __restrict__ qkv,
                                              const float* __restrict__ fc,
                                              const float* __restrict__ fs,
                                              const float* __restrict__ k_xl,
                                              const float* __restrict__ v_xl,
                                              const float* __restrict__ pos,
                                              __hip_bfloat16* __restrict__ Kc,
                                              __hip_bfloat16* __restrict__ Vc) {
    int bt = blockIdx.x;
    int b = bt >> 10, t = bt & (T_ - 1);
    int tid = threadIdx.x;
    for (int p = tid; p < D_ / 2; p += 256) {
        int h = p >> 5, i = p & 31;
        float c = fc[t * 32 + i], s = fs[t * 32 + i];
        size_t qoff = (size_t)bt * 3072 + h * 64 + 2 * i;
        float qr = qkv[qoff], qi = qkv[qoff + 1];
        qkv[qoff]     = qr * c - qi * s;
        qkv[qoff + 1] = qr * s + qi * c;
        float kr = qkv[qoff + 1024], ki = qkv[qoff + 1025];
        size_t koff = ((size_t)(b * H_ + h) * S_ + T_ + t) * HD_ + 2 * i;
        Kc[koff]     = __float2bfloat16(kr * c - ki * s);
        Kc[koff + 1] = __float2bfloat16(kr * s + ki * c);
        Vc[koff]     = __float2bfloat16(qkv[qoff + 2048]);
        Vc[koff + 1] = __float2bfloat16(qkv[qoff + 2049]);
    }
    for (int d = tid; d < D_; d += 256) {
        int h = d >> 6, dd = d & 63;
        size_t src = (size_t)bt * D_ + d;
        size_t dst = ((size_t)(b * H_ + h) * S_ + t) * HD_ + dd;
        Kc[dst] = __float2bfloat16(k_xl[src] + pos[(size_t)t * D_ + d]);
        Vc[dst] = __float2bfloat16(v_xl[src]);
    }
}

// ---------------- MFMA flash attention ----------------
__global__ __launch_bounds__(256) void k_attn_mfma(const float* __restrict__ qkv,
                                                   const __hip_bfloat16* __restrict__ Kc,
                                                   const __hip_bfloat16* __restrict__ Vc,
                                                   float* __restrict__ y,
                                                   const int* __restrict__ pcausal) {
    __shared__ __align__(16) __hip_bfloat16 Qs[64][72];
    __shared__ __align__(16) __hip_bfloat16 Ks[64][72];
    __shared__ __align__(16) __hip_bfloat16 VsT[64][72];   // [d][s]
    __shared__ __align__(16) __hip_bfloat16 Ps[4][16][72]; // per-wave [q][s]
    const int qt = blockIdx.x, bh = blockIdx.y;
    const int b = bh >> 4, h = bh & 15;
    const int tid = threadIdx.x, lane = tid & 63, wid = tid >> 6;
    const int fr = lane & 15, g = lane >> 4, fk = g << 3;
    const int causal = pcausal[0];
    const int qbase = qt << 6;

    {
        int qrow = tid >> 2, dk = (tid & 3) << 4;
        const float* src = qkv + (size_t)(b * T_ + qbase + qrow) * 3072 + h * 64 + dk;
        __hip_bfloat16* dst = &Qs[qrow][dk];
        #pragma unroll
        for (int i = 0; i < 16; i += 4) {
            float4 v = *(const float4*)(src + i);
            dst[i]   = __float2bfloat16(v.x); dst[i+1] = __float2bfloat16(v.y);
            dst[i+2] = __float2bfloat16(v.z); dst[i+3] = __float2bfloat16(v.w);
        }
    }

    const __hip_bfloat16* Kb = Kc + (size_t)bh * S_ * HD_;
    const __hip_bfloat16* Vb = Vc + (size_t)bh * S_ * HD_;
    const int krow = tid >> 2, kdk = (tid & 3) << 4;
    const int vs = tid & 63, vd0 = (tid >> 6) << 4;
    const int q_t = qbase + (wid << 4) + fr;

    float m_run = -1e30f, l_run = 0.f;
    f32x4 o0 = {0.f,0.f,0.f,0.f}, o1 = o0, o2 = o0, o3 = o0;

    for (int kt = 0; kt < 32; ++kt) {
        const int s0 = kt << 6;
        {
            const __hip_bfloat16* src = Kb + (size_t)(s0 + krow) * HD_ + kdk;
            short8 u0 = *(const short8*)src;
            short8 u1 = *(const short8*)(src + 8);
            *(short8*)&Ks[krow][kdk]     = u0;
            *(short8*)&Ks[krow][kdk + 8] = u1;
        }
        {
            const __hip_bfloat16* src = Vb + (size_t)(s0 + vs) * HD_ + vd0;
            short8 u0 = *(const short8*)src;
            short8 u1 = *(const short8*)(src + 8);
            #pragma unroll
            for (int i = 0; i < 8; i++) VsT[vd0 + i][vs]     = ((const __hip_bfloat16*)&u0)[i];
            #pragma unroll
            for (int i = 0; i < 8; i++) VsT[vd0 + 8 + i][vs] = ((const __hip_bfloat16*)&u1)[i];
        }
        __syncthreads();

        f32x4 st[4];
        #pragma unroll
        for (int ms = 0; ms < 4; ++ms) {
            f32x4 acc = {0.f,0.f,0.f,0.f};
            #pragma unroll
            for (int dk = 0; dk < 64; dk += 32) {
                short8 kf = *(const short8*)&Ks[(ms << 4) + fr][dk + fk];
                short8 qf = *(const short8*)&Qs[(wid << 4) + fr][dk + fk];
                acc = __builtin_amdgcn_mfma_f32_16x16x32_bf16(kf, qf, acc, 0, 0, 0);
            }
            st[ms] = acc;
        }

        float pmax = -1e30f;
        #pragma unroll
        for (int ms = 0; ms < 4; ++ms) {
            #pragma unroll
            for (int r = 0; r < 4; ++r) {
                float v = st[ms][r] * 0.125f;
                if (causal) {
                    int s_g = s0 + (ms << 4) + (g << 2) + r;
                    if (s_g > q_t) v = -1e30f;
                }
                st[ms][r] = v;
                pmax = fmaxf(pmax, v);
            }
        }
        pmax = fmaxf(pmax, __shfl_xor(pmax, 16));
        pmax = fmaxf(pmax, __shfl_xor(pmax, 32));

        float mnew = fmaxf(m_run, pmax);
        float scl = __expf(m_run - mnew);
        float tsum = 0.f;
        #pragma unroll
        for (int ms = 0; ms < 4; ++ms) {
            #pragma unroll
            for (int r = 0; r < 4; ++r) {
                float p = __expf(st[ms][r] - mnew);
                tsum += p;
                Ps[wid][fr][(ms << 4) + (g << 2) + r] = __float2bfloat16(p);
            }
        }
        tsum += __shfl_xor(tsum, 16);
        tsum += __shfl_xor(tsum, 32);
        l_run = l_run * scl + tsum;
        m_run = mnew;
        o0 *= scl; o1 *= scl; o2 *= scl; o3 *= scl;

        __syncthreads();

        #pragma unroll
        for (int ks = 0; ks < 64; ks += 32) {
            short8 pf = *(const short8*)&Ps[wid][fr][ks + fk];
            short8 v0 = *(const short8*)&VsT[ 0 + fr][ks + fk];
            short8 v1 = *(const short8*)&VsT[16 + fr][ks + fk];
            short8 v2 = *(const short8*)&VsT[32 + fr][ks + fk];
            short8 v3 = *(const short8*)&VsT[48 + fr][ks + fk];
            o0 = __builtin_amdgcn_mfma_f32_16x16x32_bf16(v0, pf, o0, 0, 0, 0);
            o1 = __builtin_amdgcn_mfma_f32_16x16x32_bf16(v1, pf, o1, 0, 0, 0);
            o2 = __builtin_amdgcn_mfma_f32_16x16x32_bf16(v2, pf, o2, 0, 0, 0);
            o3 = __builtin_amdgcn_mfma_f32_16x16x32_bf16(v3, pf, o3, 0, 0, 0);
        }
        __syncthreads();
    }

    float invl = (l_run > 0.f) ? (1.0f / l_run) : 0.f;
    float* yb = y + (size_t)(b * T_ + qbase + (wid << 4) + fr) * D_ + h * HD_;
    #pragma unroll
    for (int r = 0; r < 4; ++r) {
        yb[ 0 + (g << 2) + r] = o0[r] * invl;
        yb[16 + (g << 2) + r] = o1[r] * invl;
        yb[32 + (g << 2) + r] = o2[r] * invl;
        yb[48 + (g << 2) + r] = o3[r] * invl;
    }
}

// ---------------- router ----------------
__global__ __launch_bounds__(64) void k_router(const float* __restrict__ xf,
                                               const float* __restrict__ rw,
                                               const float* __restrict__ rb,
                                               float* __restrict__ gates,
                                               int* __restrict__ counts,
                                               int* __restrict__ lists) {
    int tok = blockIdx.x, lane = threadIdx.x;
    float acc[E_] = {0,0,0,0,0,0,0,0};
    for (int k = lane; k < D_; k += 64) {
        float xv = xf[(size_t)tok * D_ + k];
        const float* wr = rw + (size_t)k * E_;
        #pragma unroll
        for (int e = 0; e < E_; e++) acc[e] += xv * wr[e];
    }
    #pragma unroll
    for (int off = 32; off; off >>= 1) {
        #pragma unroll
        for (int e = 0; e < E_; e++) acc[e] += __shfl_xor(acc[e], off);
    }
    if (lane == 0) {
        float l[E_];
        #pragma unroll
        for (int e = 0; e < E_; e++) l[e] = acc[e] + rb[e];
        int i1 = 0;
        #pragma unroll
        for (int e = 1; e < E_; e++) if (l[e] > l[i1]) i1 = e;
        int i2 = -1;
        #pragma unroll
        for (int e = 0; e < E_; e++) {
            if (e == i1) continue;
            if (i2 < 0 || l[e] > l[i2]) i2 = e;
        }
        float e2 = expf(l[i2] - l[i1]);
        float den = 1.0f + e2;
        float gv[E_] = {0,0,0,0,0,0,0,0};
        gv[i1] = 1.0f / den;
        gv[i2] = e2 / den;
        #pragma unroll
        for (int e = 0; e < E_; e++) gates[(size_t)tok * E_ + e] = gv[e];
        int p1 = atomicAdd(&counts[i1], 1);
        lists[i1 * NT + p1] = tok;
        int p2 = atomicAdd(&counts[i2], 1);
        lists[i2 * NT + p2] = tok;
    }
}

__global__ __launch_bounds__(256) void k_add(const float* __restrict__ a,
                                             const float* __restrict__ b,
                                             float* __restrict__ o, int n4) {
    int i = blockIdx.x * 256 + threadIdx.x;
    if (i < n4) {
        float4 x = ((const float4*)a)[i];
        float4 y = ((const float4*)b)[i];
        float4 r;
        r.x = x.x + y.x; r.y = x.y + y.y; r.z = x.z + y.z; r.w = x.w + y.w;
        ((float4*)o)[i] = r;
    }
}

// ---------------- host ----------------
extern "C" void kernel_launch(void* const* d_in, const int* in_sizes, int n_in,
                              void* d_out, int out_size, void* d_ws, size_t ws_size,
                              hipStream_t stream) {
    (void)in_sizes; (void)n_in; (void)out_size; (void)ws_size;
    const float* q      = (const float*)d_in[0];
    const float* fc     = (const float*)d_in[3];
    const float* fs     = (const float*)d_in[4];
    const float* k_xl   = (const float*)d_in[5];
    const float* v_xl   = (const float*)d_in[6];
    const float* W_qkv  = (const float*)d_in[7];
    const float* W_proj = (const float*)d_in[8];
    const float* pos    = (const float*)d_in[9];
    const float* anw    = (const float*)d_in[10];
    const float* fnw    = (const float*)d_in[11];
    const float* rw     = (const float*)d_in[12];
    const float* rb     = (const float*)d_in[13];
    const float* w1     = (const float*)d_in[14];
    const float* w2     = (const float*)d_in[15];
    const float* w3     = (const float*)d_in[16];
    const int*   caus   = (const int*)d_in[17];

    float* ws = (float*)d_ws;
    const size_t M1 = 1u << 20;
    // Workspace map:
    float* xn    = ws;                        // [ 0M, 2M)
    float* qkv   = ws + 2*M1;                 // [ 2M, 8M)   dead after attn
    __hip_bfloat16* Kc = (__hip_bfloat16*)(ws +  8*M1);  // [ 8M,10M)  dead after attn
    __hip_bfloat16* Vc = (__hip_bfloat16*)(ws + 10*M1);  // [10M,12M)  dead after attn
    float* y2d   = ws + 12*M1;                // [12M,14M)  dead after proj
    float* h     = ws + 14*M1;                // [14M,16M)
    float* xf    = ws + 16*M1;                // [16M,18M)
    float* proj  = ws + 18*M1;                // [18M,20M)  dead after k_add(h)
    float* moe   = ws + 20*M1;                // [20M,22M)
    float* gates = ws + 22*M1;                // 16384 floats
    int*   counts= (int*)(ws + 22*M1 + 16384);
    int*   lists = counts + 8;                // 8*2048 ints
    int*   yexp  = lists + E_*NT;             // 128 ints
    int*   yrow0 = yexp + 128;                // 128 ints
    // G (bf16): YMAX*64 x FH = 4608*4096*2B = 37.75MB -> 9.44M floats, in [2M,11.44M)
    __hip_bfloat16* G = (__hip_bfloat16*)(ws + 2*M1);

    const int n2v = NT * D_ / 4;

    hipMemsetAsync(counts, 0, 8 * sizeof(int), stream);
    hipMemsetAsync(moe, 0, (size_t)NT * D_ * sizeof(float), stream);

    k_rmsnorm<<<NT, 256, 0, stream>>>(q, anw, xn);

    dim3 gqkv(3 * D_ / 64, NT / 64);
    k_gemm<<<gqkv, 256, 0, stream>>>(xn, W_qkv, qkv, NT, 3 * D_, D_);

    k_rope<<<NT, 256, 0, stream>>>(qkv, fc, fs, k_xl, v_xl, pos, Kc, Vc);

    dim3 gattn(T_ / 64, B_ * H_);
    k_attn_mfma<<<gattn, 256, 0, stream>>>(qkv, Kc, Vc, y2d, caus);

    dim3 gproj(D_ / 64, NT / 64);
    k_gemm<<<gproj, 256, 0, stream>>>(y2d, W_proj, proj, NT, D_, D_);

    k_add<<<(n2v + 255) / 256, 256, 0, stream>>>(xn, proj, h, n2v);

    k_rmsnorm<<<NT, 256, 0, stream>>>(h, fnw, xf);

    k_router<<<NT, 64, 0, stream>>>(xf, rw, rb, gates, counts, lists);

    k_ytab<<<1, 64, 0, stream>>>(counts, yexp, yrow0);

    dim3 gup(FH_ / 64, YMAX);
    k_moe_up<<<gup, 256, 0, stream>>>(xf, w1, w3, G, lists, counts, yexp, yrow0);

    dim3 gdn(D_ / 64, YMAX);
    k_moe_dn<<<gdn, 256, 0, stream>>>(G, w2, moe, lists, counts, yexp, yrow0, gates);

    k_add<<<(n2v + 255) / 256, 256, 0, stream>>>(h, moe, (float*)d_out, n2v);
}